// Round 15
// baseline (234.728 us; speedup 1.0000x reference)
//
#include <hip/hip_runtime.h>
#include <math.h>
#include <float.h>

#define NFEAT 256
#define NHID 64
#define BN_EPS 1e-5f

typedef float f32x4 __attribute__((ext_vector_type(4)));
typedef short s16x8 __attribute__((ext_vector_type(8)));

__device__ __forceinline__ float lrelu(float x) { return x >= 0.f ? x : 0.2f * x; }
__device__ __forceinline__ unsigned short f2bf(float f) {
    unsigned int u = __float_as_uint(f);
    return (unsigned short)((u + 0x7fffu + ((u >> 16) & 1u)) >> 16);
}
__device__ __forceinline__ float bf_lo(unsigned int v) { return __uint_as_float(v << 16); }
__device__ __forceinline__ float bf_hi(unsigned int v) { return __uint_as_float(v & 0xffff0000u); }

// ==================== K1: prep_w blocks + per-block hist blocks (fused) ====================
// blocks [0,128): Wt prep.  blocks [128, 128+NEB): per-block bucket counts (no atomics).
__global__ void stage1_k(const float* __restrict__ We, const float* __restrict__ Wg,
                         unsigned short* __restrict__ Wt,
                         const int* __restrict__ x, int E,
                         int* __restrict__ blkcnt) {
    if (blockIdx.x < 128) {
        int tid = blockIdx.x * 256 + threadIdx.x;       // 32768 total
        int ks  = tid >> 12;
        int col = (tid >> 5) & 127;
        int kk  = tid & 31;
        int k   = ks * 32 + kk;
        float v = (col < 64) ? We[k * 64 + col] : Wg[k * 64 + (col - 64)];
        size_t byte = (size_t)ks * 10240 + col * 80 + (kk >> 3) * 16 + (kk & 7) * 2;
        Wt[byte >> 1] = f2bf(v);
        return;
    }
    // hist: 32 edges/thread, per-block LDS counts -> plain global store
    __shared__ int lh[256];
    int blk = blockIdx.x - 128;
    int tid = threadIdx.x;
    lh[tid] = 0;
    __syncthreads();
    int base = (blk * 256 + tid) * 32;
#pragma unroll
    for (int c = 0; c < 8; ++c) {
        int b4 = base + c * 4;
        if (b4 + 4 <= E) {
            int4 d = *(const int4*)(x + E + b4);
            atomicAdd(&lh[d.x >> 9], 1); atomicAdd(&lh[d.y >> 9], 1);
            atomicAdd(&lh[d.z >> 9], 1); atomicAdd(&lh[d.w >> 9], 1);
        } else {
            for (int k = 0; k < 4; ++k)
                if (b4 + k < E) atomicAdd(&lh[x[E + b4 + k] >> 9], 1);
        }
    }
    __syncthreads();
    blkcnt[blk * 256 + tid] = lh[tid];
}

// ==================== K2: hierarchical scan ====================
// thread t = bucket t. Pass 1: per-block bases + bucket totals. Then dual
// exclusive scan over buckets (edges / edges+selfloops). Pass 2: add bucket_base.
__global__ void scan_k(int* __restrict__ blkcnt, int NEB, int M, int NBKT,
                       int* __restrict__ blkbase,
                       int* __restrict__ bcnt, int* __restrict__ bucket_base,
                       int* __restrict__ csr_base) {
    __shared__ int s_c[2][256], s_t[2][256];
    int t = threadIdx.x;
    int run = 0;
    for (int b = 0; b < NEB; ++b) {
        int c = blkcnt[b * 256 + t];
        blkbase[b * 256 + t] = run;
        run += c;
    }
    bcnt[t] = run;                      // total real edges for bucket t
    int n0 = t << 9;
    int sc = (t < NBKT) ? min(512, M - n0) : 0;
    int cc = (t < NBKT) ? run : 0;
    int tot = cc + sc;
    s_c[0][t] = cc; s_t[0][t] = tot;
    __syncthreads();
    int cur = 0;
    for (int off = 1; off < 256; off <<= 1) {
        int nc = s_c[cur][t] + (t >= off ? s_c[cur][t - off] : 0);
        int nt = s_t[cur][t] + (t >= off ? s_t[cur][t - off] : 0);
        s_c[cur ^ 1][t] = nc; s_t[cur ^ 1][t] = nt;
        __syncthreads();
        cur ^= 1;
    }
    int bb = 0;
    if (t < NBKT) {
        bb = s_c[cur][t] - cc;
        bucket_base[t] = bb;
        csr_base[t] = s_t[cur][t] - tot;
    }
    for (int b = 0; b < NEB; ++b)
        blkbase[b * 256 + t] += bb;
}

// ==================== K3: gemm blocks + scatter blocks (fused) ====================
// scatter: single pass, LDS cursors seeded from blkbase (positions pre-reserved)
__device__ void scatter_body(const int* __restrict__ x, int E, int blk,
                             const int* __restrict__ blkbase, int* __restrict__ ebuf) {
    __shared__ int lh[256];
    int tid = threadIdx.x;
    lh[tid] = blkbase[blk * 256 + tid];
    __syncthreads();
    int base = (blk * 256 + tid) * 32;
#pragma unroll
    for (int c = 0; c < 8; ++c) {
        int b4 = base + c * 4;
        if (b4 + 4 <= E) {
            int4 s = *(const int4*)(x + b4);
            int4 d = *(const int4*)(x + E + b4);
            int ss[4] = {s.x, s.y, s.z, s.w};
            int dd[4] = {d.x, d.y, d.z, d.w};
#pragma unroll
            for (int k = 0; k < 4; ++k) {
                int bk = dd[k] >> 9;
                int pos = atomicAdd(&lh[bk], 1);
                ebuf[pos] = ((dd[k] & 511) << 17) | ss[k];
            }
        } else {
            for (int k = 0; k < 4; ++k) {
                int i = b4 + k;
                if (i < E) {
                    int sv = x[i], dv = x[E + i];
                    int bk = dv >> 9;
                    int pos = atomicAdd(&lh[bk], 1);
                    ebuf[pos] = ((dv & 511) << 17) | sv;
                }
            }
        }
    }
}

__global__ __launch_bounds__(256) void stage3_k(const float* __restrict__ g,
                                                const char* __restrict__ Wt,
                                                unsigned short* __restrict__ hh,
                                                const float* __restrict__ ase,
                                                const float* __restrict__ ade,
                                                const float* __restrict__ asg,
                                                const float* __restrict__ adg,
                                                float2* __restrict__ esrc,
                                                float2* __restrict__ edst, int M, int GB,
                                                const int* __restrict__ x, int E,
                                                const int* __restrict__ blkbase,
                                                int* __restrict__ ebuf) {
    __shared__ __align__(16) char lds[21504];
    if (blockIdx.x >= (unsigned)GB) {
        scatter_body(x, E, blockIdx.x - GB, blkbase, ebuf);
        return;
    }
    char* As = lds;            // [128 rows][80B] bf16
    char* Bs = lds + 10240;    // [128 cols][80B]
    float* av = (float*)(lds + 20480);   // [256]: ase|ade|asg|adg
    const int tid = threadIdx.x;
    const int l = tid & 63;
    const int w = tid >> 6;
    const int row0 = blockIdx.x * 128;

    {
        float v;
        if (tid < 64)       v = ase[tid];
        else if (tid < 128) v = ade[tid - 64];
        else if (tid < 192) v = asg[tid - 128];
        else                v = adg[tid - 192];
        av[tid] = v;
    }

    f32x4 acc[2][8];
#pragma unroll
    for (int r = 0; r < 2; r++)
#pragma unroll
        for (int n = 0; n < 8; n++) acc[r][n] = (f32x4){0.f, 0.f, 0.f, 0.f};

    const int arow = tid >> 1;
    const int ah = tid & 1;
    const int grow = row0 + arow;
    const float* gp = g + (size_t)grow * NFEAT + ah * 16;
    const char* wp = Wt + arow * 80 + ah * 32;

    float4 v0 = make_float4(0.f, 0.f, 0.f, 0.f), v1 = v0, v2 = v0, v3 = v0;
    s16x8 b0, b1;
    if (grow < M) {
        v0 = *(const float4*)(gp + 0);
        v1 = *(const float4*)(gp + 4);
        v2 = *(const float4*)(gp + 8);
        v3 = *(const float4*)(gp + 12);
    }
    b0 = *(const s16x8*)(wp);
    b1 = *(const s16x8*)(wp + 16);

    for (int ks = 0; ks < 8; ++ks) {
        {
            s16x8 c0, c1;
            c0[0]=f2bf(v0.x); c0[1]=f2bf(v0.y); c0[2]=f2bf(v0.z); c0[3]=f2bf(v0.w);
            c0[4]=f2bf(v1.x); c0[5]=f2bf(v1.y); c0[6]=f2bf(v1.z); c0[7]=f2bf(v1.w);
            c1[0]=f2bf(v2.x); c1[1]=f2bf(v2.y); c1[2]=f2bf(v2.z); c1[3]=f2bf(v2.w);
            c1[4]=f2bf(v3.x); c1[5]=f2bf(v3.y); c1[6]=f2bf(v3.z); c1[7]=f2bf(v3.w);
            *(s16x8*)(As + arow * 80 + ah * 32)      = c0;
            *(s16x8*)(As + arow * 80 + ah * 32 + 16) = c1;
            *(s16x8*)(Bs + arow * 80 + ah * 32)      = b0;
            *(s16x8*)(Bs + arow * 80 + ah * 32 + 16) = b1;
        }
        __syncthreads();
        if (ks < 7) {
            const float* gpn = gp + (ks + 1) * 32;
            const char* wpn = wp + (size_t)(ks + 1) * 10240;
            v0 = make_float4(0.f, 0.f, 0.f, 0.f); v1 = v0; v2 = v0; v3 = v0;
            if (grow < M) {
                v0 = *(const float4*)(gpn + 0);
                v1 = *(const float4*)(gpn + 4);
                v2 = *(const float4*)(gpn + 8);
                v3 = *(const float4*)(gpn + 12);
            }
            b0 = *(const s16x8*)(wpn);
            b1 = *(const s16x8*)(wpn + 16);
        }
        s16x8 af[2];
#pragma unroll
        for (int r = 0; r < 2; r++)
            af[r] = *(const s16x8*)(As + (w * 32 + r * 16 + (l & 15)) * 80 + (l >> 4) * 16);
#pragma unroll
        for (int n = 0; n < 8; n++) {
            s16x8 bf = *(const s16x8*)(Bs + (n * 16 + (l & 15)) * 80 + (l >> 4) * 16);
            acc[0][n] = __builtin_amdgcn_mfma_f32_16x16x32_bf16(af[0], bf, acc[0][n], 0, 0, 0);
            acc[1][n] = __builtin_amdgcn_mfma_f32_16x16x32_bf16(af[1], bf, acc[1][n], 0, 0, 0);
        }
        __syncthreads();
    }

    float vs_e[4], vd_e[4], vs_g[4], vd_g[4];
    {
        const int l16 = l & 15;
#pragma unroll
        for (int n = 0; n < 4; ++n) {
            vs_e[n] = av[n * 16 + l16];
            vd_e[n] = av[64 + n * 16 + l16];
            vs_g[n] = av[128 + n * 16 + l16];
            vd_g[n] = av[192 + n * 16 + l16];
        }
    }

    unsigned short* epi = (unsigned short*)lds;   // [64][128] bf16
#pragma unroll
    for (int p = 0; p < 2; ++p) {
        {
            float pse[4] = {0,0,0,0}, pde[4] = {0,0,0,0};
            float psg[4] = {0,0,0,0}, pdg[4] = {0,0,0,0};
#pragma unroll
            for (int n = 0; n < 4; ++n)
#pragma unroll
                for (int j = 0; j < 4; ++j) {
                    float he = acc[p][n][j];
                    float hg = acc[p][n + 4][j];
                    pse[j] += he * vs_e[n];
                    pde[j] += he * vd_e[n];
                    psg[j] += hg * vs_g[n];
                    pdg[j] += hg * vd_g[n];
                }
#pragma unroll
            for (int off = 1; off <= 8; off <<= 1) {
#pragma unroll
                for (int j = 0; j < 4; ++j) {
                    pse[j] += __shfl_xor(pse[j], off, 64);
                    pde[j] += __shfl_xor(pde[j], off, 64);
                    psg[j] += __shfl_xor(psg[j], off, 64);
                    pdg[j] += __shfl_xor(pdg[j], off, 64);
                }
            }
            if ((l & 15) == 0) {
#pragma unroll
                for (int j = 0; j < 4; ++j) {
                    int gr = row0 + w * 32 + p * 16 + (l >> 4) * 4 + j;
                    if (gr < M) {
                        esrc[gr] = make_float2(pse[j], psg[j]);
                        edst[gr] = make_float2(pde[j], pdg[j]);
                    }
                }
            }
        }
#pragma unroll
        for (int n = 0; n < 8; n++)
#pragma unroll
            for (int j = 0; j < 4; j++)
                epi[(w * 16 + (l >> 4) * 4 + j) * 128 + n * 16 + (l & 15)] = f2bf(acc[p][n][j]);
        __syncthreads();
        int er = tid >> 2, sgm = tid & 3;
        int grow2 = row0 + 32 * (er >> 4) + 16 * p + (er & 15);
        if (grow2 < M) {
            const s16x8* src = (const s16x8*)(epi + er * 128 + sgm * 32);
            s16x8* dst = (s16x8*)(hh + (size_t)grow2 * 128 + sgm * 32);
#pragma unroll
            for (int q = 0; q < 4; q++) dst[q] = src[q];
        }
        __syncthreads();
    }
}

// ==================== K4: bucket CSR finalize ====================
__global__ __launch_bounds__(256) void bucket_csr_k(const int* __restrict__ bcnt,
                                                    const int* __restrict__ bucket_base,
                                                    const int* __restrict__ csr_base,
                                                    const int* __restrict__ ebuf, int M,
                                                    int* __restrict__ row_start,
                                                    int* __restrict__ deg,
                                                    int* __restrict__ srcs) {
    int b = blockIdx.x, tid = threadIdx.x;
    int nE = bcnt[b];
    int ebase = bucket_base[b];
    int cbase = csr_base[b];
    int n0 = b << 9;
    int nloc = min(512, M - n0);
    __shared__ int cnt[512], sa[512], sb[512], cur[512];
#pragma unroll
    for (int k = 0; k < 2; ++k) {
        int i = tid + k * 256;
        cnt[i] = (i < nloc) ? 1 : 0;   // self loop
    }
    __syncthreads();
    for (int j = tid; j < nE; j += 256)
        atomicAdd(&cnt[ebuf[ebase + j] >> 17], 1);
    __syncthreads();
#pragma unroll
    for (int k = 0; k < 2; ++k) { int i = tid + k * 256; sa[i] = cnt[i]; }
    __syncthreads();
    int* a = sa; int* bb = sb;
    for (int off = 1; off < 512; off <<= 1) {
#pragma unroll
        for (int k = 0; k < 2; ++k) {
            int i = tid + k * 256;
            bb[i] = a[i] + (i >= off ? a[i - off] : 0);
        }
        __syncthreads();
        int* t = a; a = bb; bb = t;
    }
#pragma unroll
    for (int k = 0; k < 2; ++k) {
        int i = tid + k * 256;
        int excl = a[i] - cnt[i];
        cur[i] = excl;
        if (i < nloc) {
            row_start[n0 + i] = cbase + excl;
            deg[n0 + i] = cnt[i];
            srcs[cbase + excl] = n0 + i;   // self loop first
            cur[i] = excl + 1;
        }
    }
    __syncthreads();
    for (int j = tid; j < nE; j += 256) {
        int p = ebuf[ebase + j];
        int dl = p >> 17, src = p & 0x1FFFF;
        int pos = atomicAdd(&cur[dl], 1);
        srcs[cbase + pos] = src;
    }
}

// ==================== K5: per-node quarter-wave gather + fused finalize ====================
__global__ void node_acc_k(const int* __restrict__ srcs, const int* __restrict__ row_start,
                           const int* __restrict__ deg,
                           const float2* __restrict__ esrc, const float2* __restrict__ edst,
                           const unsigned short* __restrict__ hh,
                           const float* __restrict__ be, const float* __restrict__ ge,
                           const float* __restrict__ bte, const float* __restrict__ rme,
                           const float* __restrict__ rve,
                           const float* __restrict__ bg, const float* __restrict__ gg,
                           const float* __restrict__ btg, const float* __restrict__ rmg,
                           const float* __restrict__ rvg,
                           const float* __restrict__ clsW, const float* __restrict__ clsb,
                           float* __restrict__ y, float* __restrict__ s_out, int M) {
    int n = blockIdx.x * 4 + (threadIdx.x >> 6);
    int l = threadIdx.x & 63;
    if (n >= M) return;
    int beg = row_start[n];
    int cnt = deg[n];
    int qh = l >> 4;
    int li = l & 15;
    int layer = li >> 3;
    float2 ed = edst[n];
    float edv = layer ? ed.y : ed.x;
    const int* sp = srcs + beg;
    const char* hb = (const char*)hh + (unsigned)li * 16;
    float a0 = 0.f, a1 = 0.f, a2 = 0.f, a3 = 0.f;
    float a4 = 0.f, a5 = 0.f, a6 = 0.f, a7 = 0.f, zacc = 0.f;
    int j = 0;
    for (; j + 16 <= cnt; j += 16) {
        int s0 = sp[j + qh];
        int s1 = sp[j + 4 + qh];
        int s2 = sp[j + 8 + qh];
        int s3 = sp[j + 12 + qh];
        float2 e0 = esrc[s0], e1 = esrc[s1], e2 = esrc[s2], e3 = esrc[s3];
        uint4 h0 = *(const uint4*)(hb + ((size_t)(unsigned)s0 << 8));
        uint4 h1 = *(const uint4*)(hb + ((size_t)(unsigned)s1 << 8));
        uint4 h2 = *(const uint4*)(hb + ((size_t)(unsigned)s2 << 8));
        uint4 h3 = *(const uint4*)(hb + ((size_t)(unsigned)s3 << 8));
        float p0 = __expf(lrelu((layer ? e0.y : e0.x) + edv));
        float p1 = __expf(lrelu((layer ? e1.y : e1.x) + edv));
        float p2 = __expf(lrelu((layer ? e2.y : e2.x) + edv));
        float p3 = __expf(lrelu((layer ? e3.y : e3.x) + edv));
        zacc += (p0 + p1) + (p2 + p3);
        a0 += p0 * bf_lo(h0.x); a1 += p0 * bf_hi(h0.x);
        a2 += p0 * bf_lo(h0.y); a3 += p0 * bf_hi(h0.y);
        a4 += p0 * bf_lo(h0.z); a5 += p0 * bf_hi(h0.z);
        a6 += p0 * bf_lo(h0.w); a7 += p0 * bf_hi(h0.w);
        a0 += p1 * bf_lo(h1.x); a1 += p1 * bf_hi(h1.x);
        a2 += p1 * bf_lo(h1.y); a3 += p1 * bf_hi(h1.y);
        a4 += p1 * bf_lo(h1.z); a5 += p1 * bf_hi(h1.z);
        a6 += p1 * bf_lo(h1.w); a7 += p1 * bf_hi(h1.w);
        a0 += p2 * bf_lo(h2.x); a1 += p2 * bf_hi(h2.x);
        a2 += p2 * bf_lo(h2.y); a3 += p2 * bf_hi(h2.y);
        a4 += p2 * bf_lo(h2.z); a5 += p2 * bf_hi(h2.z);
        a6 += p2 * bf_lo(h2.w); a7 += p2 * bf_hi(h2.w);
        a0 += p3 * bf_lo(h3.x); a1 += p3 * bf_hi(h3.x);
        a2 += p3 * bf_lo(h3.y); a3 += p3 * bf_hi(h3.y);
        a4 += p3 * bf_lo(h3.z); a5 += p3 * bf_hi(h3.z);
        a6 += p3 * bf_lo(h3.w); a7 += p3 * bf_hi(h3.w);
    }
    for (; j + 8 <= cnt; j += 8) {
        int s0 = sp[j + qh];
        int s1 = sp[j + 4 + qh];
        float2 e0 = esrc[s0];
        float2 e1 = esrc[s1];
        uint4 h0 = *(const uint4*)(hb + ((size_t)(unsigned)s0 << 8));
        uint4 h1 = *(const uint4*)(hb + ((size_t)(unsigned)s1 << 8));
        float p0 = __expf(lrelu((layer ? e0.y : e0.x) + edv));
        float p1 = __expf(lrelu((layer ? e1.y : e1.x) + edv));
        zacc += p0 + p1;
        a0 += p0 * bf_lo(h0.x); a1 += p0 * bf_hi(h0.x);
        a2 += p0 * bf_lo(h0.y); a3 += p0 * bf_hi(h0.y);
        a4 += p0 * bf_lo(h0.z); a5 += p0 * bf_hi(h0.z);
        a6 += p0 * bf_lo(h0.w); a7 += p0 * bf_hi(h0.w);
        a0 += p1 * bf_lo(h1.x); a1 += p1 * bf_hi(h1.x);
        a2 += p1 * bf_lo(h1.y); a3 += p1 * bf_hi(h1.y);
        a4 += p1 * bf_lo(h1.z); a5 += p1 * bf_hi(h1.z);
        a6 += p1 * bf_lo(h1.w); a7 += p1 * bf_hi(h1.w);
    }
    for (; j < cnt; j += 4) {
        int idx = j + qh;
        if (idx < cnt) {
            int s = sp[idx];
            float2 e = esrc[s];
            uint4 h = *(const uint4*)(hb + ((size_t)(unsigned)s << 8));
            float p = __expf(lrelu((layer ? e.y : e.x) + edv));
            zacc += p;
            a0 += p * bf_lo(h.x); a1 += p * bf_hi(h.x);
            a2 += p * bf_lo(h.y); a3 += p * bf_hi(h.y);
            a4 += p * bf_lo(h.z); a5 += p * bf_hi(h.z);
            a6 += p * bf_lo(h.w); a7 += p * bf_hi(h.w);
        }
    }
    a0 += __shfl_xor(a0, 16, 64); a0 += __shfl_xor(a0, 32, 64);
    a1 += __shfl_xor(a1, 16, 64); a1 += __shfl_xor(a1, 32, 64);
    a2 += __shfl_xor(a2, 16, 64); a2 += __shfl_xor(a2, 32, 64);
    a3 += __shfl_xor(a3, 16, 64); a3 += __shfl_xor(a3, 32, 64);
    a4 += __shfl_xor(a4, 16, 64); a4 += __shfl_xor(a4, 32, 64);
    a5 += __shfl_xor(a5, 16, 64); a5 += __shfl_xor(a5, 32, 64);
    a6 += __shfl_xor(a6, 16, 64); a6 += __shfl_xor(a6, 32, 64);
    a7 += __shfl_xor(a7, 16, 64); a7 += __shfl_xor(a7, 32, 64);
    zacc += __shfl_xor(zacc, 16, 64); zacc += __shfl_xor(zacc, 32, 64);

    if (qh == 0) {
        float rz = 1.f / zacc;
        float o0 = a0 * rz, o1 = a1 * rz, o2 = a2 * rz, o3 = a3 * rz;
        float o4 = a4 * rz, o5 = a5 * rz, o6 = a6 * rz, o7 = a7 * rz;
        int cb = (li & 7) * 2;
        const float4* bp  = (const float4*)(layer ? bg  : be);
        const float4* rmp = (const float4*)(layer ? rmg : rme);
        const float4* rvp = (const float4*)(layer ? rvg : rve);
        const float4* gp4 = (const float4*)(layer ? gg  : ge);
        const float4* btp = (const float4*)(layer ? btg : bte);
        float4 bA = bp[cb],  bB = bp[cb + 1];
        float4 rmA = rmp[cb], rmB = rmp[cb + 1];
        float4 rvA = rvp[cb], rvB = rvp[cb + 1];
        float4 gA = gp4[cb],  gB = gp4[cb + 1];
        float4 btA = btp[cb], btB = btp[cb + 1];
        o0 = (fmaxf(o0 + bA.x, 0.f) - rmA.x) * rsqrtf(rvA.x + BN_EPS) * gA.x + btA.x;
        o1 = (fmaxf(o1 + bA.y, 0.f) - rmA.y) * rsqrtf(rvA.y + BN_EPS) * gA.y + btA.y;
        o2 = (fmaxf(o2 + bA.z, 0.f) - rmA.z) * rsqrtf(rvA.z + BN_EPS) * gA.z + btA.z;
        o3 = (fmaxf(o3 + bA.w, 0.f) - rmA.w) * rsqrtf(rvA.w + BN_EPS) * gA.w + btA.w;
        o4 = (fmaxf(o4 + bB.x, 0.f) - rmB.x) * rsqrtf(rvB.x + BN_EPS) * gB.x + btB.x;
        o5 = (fmaxf(o5 + bB.y, 0.f) - rmB.y) * rsqrtf(rvB.y + BN_EPS) * gB.y + btB.y;
        o6 = (fmaxf(o6 + bB.z, 0.f) - rmB.z) * rsqrtf(rvB.z + BN_EPS) * gB.z + btB.z;
        o7 = (fmaxf(o7 + bB.w, 0.f) - rmB.w) * rsqrtf(rvB.w + BN_EPS) * gB.w + btB.w;
        if (layer == 0) {
            float4* so = (float4*)(s_out + (size_t)n * 64 + (li & 7) * 8);
            so[0] = make_float4(o0, o1, o2, o3);
            so[1] = make_float4(o4, o5, o6, o7);
        } else {
            float4 wA = ((const float4*)clsW)[cb];
            float4 wB = ((const float4*)clsW)[cb + 1];
            float t = o0 * wA.x + o1 * wA.y + o2 * wA.z + o3 * wA.w
                    + o4 * wB.x + o5 * wB.y + o6 * wB.z + o7 * wB.w;
            t += __shfl_xor(t, 1, 64);
            t += __shfl_xor(t, 2, 64);
            t += __shfl_xor(t, 4, 64);
            if (li == 8) y[n] = t + clsb[0];
        }
    }
}

extern "C" void kernel_launch(void* const* d_in, const int* in_sizes, int n_in,
                              void* d_out, int out_size, void* d_ws, size_t ws_size,
                              hipStream_t stream) {
    const float* g        = (const float*)d_in[0];
    const int*   x        = (const int*)d_in[1];
    const float* est_W    = (const float*)d_in[2];
    const float* est_asrc = (const float*)d_in[3];
    const float* est_adst = (const float*)d_in[4];
    const float* est_bias = (const float*)d_in[5];
    const float* est_gamma= (const float*)d_in[6];
    const float* est_beta = (const float*)d_in[7];
    const float* est_rmean= (const float*)d_in[8];
    const float* est_rvar = (const float*)d_in[9];
    const float* gnn_W    = (const float*)d_in[10];
    const float* gnn_asrc = (const float*)d_in[11];
    const float* gnn_adst = (const float*)d_in[12];
    const float* gnn_bias = (const float*)d_in[13];
    const float* gnn_gamma= (const float*)d_in[14];
    const float* gnn_beta = (const float*)d_in[15];
    const float* gnn_rmean= (const float*)d_in[16];
    const float* gnn_rvar = (const float*)d_in[17];
    const float* cls_W    = (const float*)d_in[18];
    const float* cls_b    = (const float*)d_in[19];

    const int M  = in_sizes[0] / NFEAT;   // 100000
    const int E  = in_sizes[1] / 2;       // 1600000
    const int Et = E + M;
    const int NBKT = (M + 511) >> 9;      // 196
    const int NEB  = (E + 8191) / 8192;   // edge blocks (32 edges/thread) = 196
    const int GB   = (M + 127) / 128;     // gemm blocks = 782

    float* y_out = (float*)d_out;         // [M]
    float* s_out = y_out + M;             // [M*64]

    char* base = (char*)d_ws;
    unsigned short* hh = (unsigned short*)base;                 // M*128 bf16
    size_t off = (size_t)M * 128 * 2;
    char* Wt = base + off;                  off += 81920;
    float2* esrc = (float2*)(base + off);   off += (size_t)M * 8;
    float2* edst = (float2*)(base + off);   off += (size_t)M * 8;
    int* deg       = (int*)(base + off);    off += (size_t)M * 4;
    int* row_start = (int*)(base + off);    off += (size_t)M * 4;
    int* srcs      = (int*)(base + off);    off += (size_t)Et * 4;
    int* ebuf      = (int*)(base + off);    off += (size_t)E * 4;
    int* blkcnt    = (int*)(base + off);    off += (size_t)NEB * 256 * 4;
    int* blkbase   = (int*)(base + off);    off += (size_t)NEB * 256 * 4;
    int* bcnt        = (int*)(base + off);  off += 256 * 4;
    int* bucket_base = (int*)(base + off);  off += 256 * 4;
    int* csr_base    = (int*)(base + off);  off += 256 * 4;

    stage1_k<<<128 + NEB, 256, 0, stream>>>(est_W, gnn_W, (unsigned short*)Wt,
                                            x, E, blkcnt);
    scan_k<<<1, 256, 0, stream>>>(blkcnt, NEB, M, NBKT, blkbase,
                                  bcnt, bucket_base, csr_base);
    stage3_k<<<GB + NEB, 256, 0, stream>>>(g, Wt, hh,
                                           est_asrc, est_adst, gnn_asrc, gnn_adst,
                                           esrc, edst, M, GB, x, E, blkbase, ebuf);
    bucket_csr_k<<<NBKT, 256, 0, stream>>>(bcnt, bucket_base, csr_base, ebuf, M,
                                           row_start, deg, srcs);
    node_acc_k<<<(M + 3) / 4, 256, 0, stream>>>(srcs, row_start, deg, esrc, edst, hh,
                                                est_bias, est_gamma, est_beta, est_rmean, est_rvar,
                                                gnn_bias, gnn_gamma, gnn_beta, gnn_rmean, gnn_rvar,
                                                cls_W, cls_b, y_out, s_out, M);
}

// Round 16
// 168.205 us; speedup vs baseline: 1.3955x; 1.3955x over previous
//
#include <hip/hip_runtime.h>
#include <math.h>
#include <float.h>

#define NFEAT 256
#define NHID 64
#define BN_EPS 1e-5f

typedef float f32x4 __attribute__((ext_vector_type(4)));
typedef short s16x8 __attribute__((ext_vector_type(8)));

__device__ __forceinline__ float lrelu(float x) { return x >= 0.f ? x : 0.2f * x; }
__device__ __forceinline__ unsigned short f2bf(float f) {
    unsigned int u = __float_as_uint(f);
    return (unsigned short)((u + 0x7fffu + ((u >> 16) & 1u)) >> 16);
}
__device__ __forceinline__ float bf_lo(unsigned int v) { return __uint_as_float(v << 16); }
__device__ __forceinline__ float bf_hi(unsigned int v) { return __uint_as_float(v & 0xffff0000u); }

// ==================== W prep (+ bcnt zeroing in block 0) ====================
__global__ void prep_w_k(const float* __restrict__ We, const float* __restrict__ Wg,
                         unsigned short* __restrict__ Wt, int* __restrict__ bcnt) {
    if (blockIdx.x == 0) bcnt[threadIdx.x] = 0;
    int tid = blockIdx.x * 256 + threadIdx.x;       // 32768 total
    int ks  = tid >> 12;
    int col = (tid >> 5) & 127;
    int kk  = tid & 31;
    int k   = ks * 32 + kk;
    float v = (col < 64) ? We[k * 64 + col] : Wg[k * 64 + (col - 64)];
    size_t byte = (size_t)ks * 10240 + col * 80 + (kk >> 3) * 16 + (kk & 7) * 2;
    Wt[byte >> 1] = f2bf(v);
}

// ==================== hist: 32 edges/thread ====================
__global__ void bucket_hist_k(const int* __restrict__ x, int E, int* __restrict__ bcnt) {
    __shared__ int lh[256];
    int tid = threadIdx.x;
    lh[tid] = 0;
    __syncthreads();
    int base = (blockIdx.x * 256 + tid) * 32;
#pragma unroll
    for (int c = 0; c < 8; ++c) {
        int b4 = base + c * 4;
        if (b4 + 4 <= E) {
            int4 d = *(const int4*)(x + E + b4);
            atomicAdd(&lh[d.x >> 9], 1); atomicAdd(&lh[d.y >> 9], 1);
            atomicAdd(&lh[d.z >> 9], 1); atomicAdd(&lh[d.w >> 9], 1);
        } else {
            for (int k = 0; k < 4; ++k)
                if (b4 + k < E) atomicAdd(&lh[x[E + b4 + k] >> 9], 1);
        }
    }
    __syncthreads();
    if (lh[tid] > 0) atomicAdd(&bcnt[tid], lh[tid]);
}

__global__ void bucket_scan_k(const int* __restrict__ bcnt, int M, int NBKT,
                              int* __restrict__ bucket_base, int* __restrict__ bcursor,
                              int* __restrict__ csr_base) {
    __shared__ int s_c[2][256], s_t[2][256];
    int tid = threadIdx.x;
    int c = (tid < NBKT) ? bcnt[tid] : 0;
    int n0 = tid << 9;
    int sc = (tid < NBKT) ? min(512, M - n0) : 0;
    int tot = c + sc;
    s_c[0][tid] = c; s_t[0][tid] = tot;
    __syncthreads();
    int cur = 0;
    for (int off = 1; off < 256; off <<= 1) {
        int nc = s_c[cur][tid] + (tid >= off ? s_c[cur][tid - off] : 0);
        int nt = s_t[cur][tid] + (tid >= off ? s_t[cur][tid - off] : 0);
        s_c[cur ^ 1][tid] = nc; s_t[cur ^ 1][tid] = nt;
        __syncthreads();
        cur ^= 1;
    }
    if (tid < NBKT) {
        int eb = s_c[cur][tid] - c;
        bucket_base[tid] = eb;
        bcursor[tid] = eb;
        csr_base[tid] = s_t[cur][tid] - tot;
    }
}

// ==================== scatter body: 32 edges/thread, two-pass (round-14 verbatim) ====================
__device__ void scatter_body(const int* __restrict__ x, int E, int blk,
                             int* __restrict__ bcursor, int* __restrict__ ebuf,
                             int* lh, int* gb) {
    int tid = threadIdx.x;
    lh[tid] = 0;
    __syncthreads();
    int base = (blk * 256 + tid) * 32;
    // pass 1: per-bucket counts
#pragma unroll
    for (int c = 0; c < 8; ++c) {
        int b4 = base + c * 4;
        if (b4 + 4 <= E) {
            int4 d = *(const int4*)(x + E + b4);
            atomicAdd(&lh[d.x >> 9], 1); atomicAdd(&lh[d.y >> 9], 1);
            atomicAdd(&lh[d.z >> 9], 1); atomicAdd(&lh[d.w >> 9], 1);
        } else {
            for (int k = 0; k < 4; ++k)
                if (b4 + k < E) atomicAdd(&lh[x[E + b4 + k] >> 9], 1);
        }
    }
    __syncthreads();
    if (lh[tid] > 0) gb[tid] = atomicAdd(&bcursor[tid], lh[tid]);
    lh[tid] = 0;                       // reuse as intra-block cursor
    __syncthreads();
    // pass 2: rank + packed write
#pragma unroll
    for (int c = 0; c < 8; ++c) {
        int b4 = base + c * 4;
        if (b4 + 4 <= E) {
            int4 s = *(const int4*)(x + b4);
            int4 d = *(const int4*)(x + E + b4);
            int ss[4] = {s.x, s.y, s.z, s.w};
            int dd[4] = {d.x, d.y, d.z, d.w};
#pragma unroll
            for (int k = 0; k < 4; ++k) {
                int bk = dd[k] >> 9;
                int rk = atomicAdd(&lh[bk], 1);
                ebuf[gb[bk] + rk] = ((dd[k] & 511) << 17) | ss[k];
            }
        } else {
            for (int k = 0; k < 4; ++k) {
                int i = b4 + k;
                if (i < E) {
                    int sv = x[i], dv = x[E + i];
                    int bk = dv >> 9;
                    int rk = atomicAdd(&lh[bk], 1);
                    ebuf[gb[bk] + rk] = ((dv & 511) << 17) | sv;
                }
            }
        }
    }
}

// ==================== stage3: gemm blocks + scatter blocks (fused dispatch) ====================
__global__ __launch_bounds__(256) void stage3_k(const float* __restrict__ g,
                                                const char* __restrict__ Wt,
                                                unsigned short* __restrict__ hh,
                                                const float* __restrict__ ase,
                                                const float* __restrict__ ade,
                                                const float* __restrict__ asg,
                                                const float* __restrict__ adg,
                                                float2* __restrict__ esrc,
                                                float2* __restrict__ edst, int M, int GB,
                                                const int* __restrict__ x, int E,
                                                int* __restrict__ bcursor,
                                                int* __restrict__ ebuf) {
    __shared__ __align__(16) char lds[21504];
    __shared__ int sc_lh[256], sc_gb[256];
    if (blockIdx.x >= (unsigned)GB) {
        scatter_body(x, E, blockIdx.x - GB, bcursor, ebuf, sc_lh, sc_gb);
        return;
    }
    char* As = lds;            // [128 rows][80B] bf16
    char* Bs = lds + 10240;    // [128 cols][80B]
    float* av = (float*)(lds + 20480);   // [256]: ase|ade|asg|adg
    const int tid = threadIdx.x;
    const int l = tid & 63;
    const int w = tid >> 6;
    const int row0 = blockIdx.x * 128;

    {
        float v;
        if (tid < 64)       v = ase[tid];
        else if (tid < 128) v = ade[tid - 64];
        else if (tid < 192) v = asg[tid - 128];
        else                v = adg[tid - 192];
        av[tid] = v;
    }

    f32x4 acc[2][8];
#pragma unroll
    for (int r = 0; r < 2; r++)
#pragma unroll
        for (int n = 0; n < 8; n++) acc[r][n] = (f32x4){0.f, 0.f, 0.f, 0.f};

    const int arow = tid >> 1;
    const int ah = tid & 1;
    const int grow = row0 + arow;
    const float* gp = g + (size_t)grow * NFEAT + ah * 16;
    const char* wp = Wt + arow * 80 + ah * 32;

    float4 v0 = make_float4(0.f, 0.f, 0.f, 0.f), v1 = v0, v2 = v0, v3 = v0;
    s16x8 b0, b1;
    if (grow < M) {
        v0 = *(const float4*)(gp + 0);
        v1 = *(const float4*)(gp + 4);
        v2 = *(const float4*)(gp + 8);
        v3 = *(const float4*)(gp + 12);
    }
    b0 = *(const s16x8*)(wp);
    b1 = *(const s16x8*)(wp + 16);

    for (int ks = 0; ks < 8; ++ks) {
        {
            s16x8 c0, c1;
            c0[0]=f2bf(v0.x); c0[1]=f2bf(v0.y); c0[2]=f2bf(v0.z); c0[3]=f2bf(v0.w);
            c0[4]=f2bf(v1.x); c0[5]=f2bf(v1.y); c0[6]=f2bf(v1.z); c0[7]=f2bf(v1.w);
            c1[0]=f2bf(v2.x); c1[1]=f2bf(v2.y); c1[2]=f2bf(v2.z); c1[3]=f2bf(v2.w);
            c1[4]=f2bf(v3.x); c1[5]=f2bf(v3.y); c1[6]=f2bf(v3.z); c1[7]=f2bf(v3.w);
            *(s16x8*)(As + arow * 80 + ah * 32)      = c0;
            *(s16x8*)(As + arow * 80 + ah * 32 + 16) = c1;
            *(s16x8*)(Bs + arow * 80 + ah * 32)      = b0;
            *(s16x8*)(Bs + arow * 80 + ah * 32 + 16) = b1;
        }
        __syncthreads();
        if (ks < 7) {
            const float* gpn = gp + (ks + 1) * 32;
            const char* wpn = wp + (size_t)(ks + 1) * 10240;
            v0 = make_float4(0.f, 0.f, 0.f, 0.f); v1 = v0; v2 = v0; v3 = v0;
            if (grow < M) {
                v0 = *(const float4*)(gpn + 0);
                v1 = *(const float4*)(gpn + 4);
                v2 = *(const float4*)(gpn + 8);
                v3 = *(const float4*)(gpn + 12);
            }
            b0 = *(const s16x8*)(wpn);
            b1 = *(const s16x8*)(wpn + 16);
        }
        s16x8 af[2];
#pragma unroll
        for (int r = 0; r < 2; r++)
            af[r] = *(const s16x8*)(As + (w * 32 + r * 16 + (l & 15)) * 80 + (l >> 4) * 16);
#pragma unroll
        for (int n = 0; n < 8; n++) {
            s16x8 bf = *(const s16x8*)(Bs + (n * 16 + (l & 15)) * 80 + (l >> 4) * 16);
            acc[0][n] = __builtin_amdgcn_mfma_f32_16x16x32_bf16(af[0], bf, acc[0][n], 0, 0, 0);
            acc[1][n] = __builtin_amdgcn_mfma_f32_16x16x32_bf16(af[1], bf, acc[1][n], 0, 0, 0);
        }
        __syncthreads();
    }

    float vs_e[4], vd_e[4], vs_g[4], vd_g[4];
    {
        const int l16 = l & 15;
#pragma unroll
        for (int n = 0; n < 4; ++n) {
            vs_e[n] = av[n * 16 + l16];
            vd_e[n] = av[64 + n * 16 + l16];
            vs_g[n] = av[128 + n * 16 + l16];
            vd_g[n] = av[192 + n * 16 + l16];
        }
    }

    unsigned short* epi = (unsigned short*)lds;   // [64][128] bf16
#pragma unroll
    for (int p = 0; p < 2; ++p) {
        {
            float pse[4] = {0,0,0,0}, pde[4] = {0,0,0,0};
            float psg[4] = {0,0,0,0}, pdg[4] = {0,0,0,0};
#pragma unroll
            for (int n = 0; n < 4; ++n)
#pragma unroll
                for (int j = 0; j < 4; ++j) {
                    float he = acc[p][n][j];
                    float hg = acc[p][n + 4][j];
                    pse[j] += he * vs_e[n];
                    pde[j] += he * vd_e[n];
                    psg[j] += hg * vs_g[n];
                    pdg[j] += hg * vd_g[n];
                }
#pragma unroll
            for (int off = 1; off <= 8; off <<= 1) {
#pragma unroll
                for (int j = 0; j < 4; ++j) {
                    pse[j] += __shfl_xor(pse[j], off, 64);
                    pde[j] += __shfl_xor(pde[j], off, 64);
                    psg[j] += __shfl_xor(psg[j], off, 64);
                    pdg[j] += __shfl_xor(pdg[j], off, 64);
                }
            }
            if ((l & 15) == 0) {
#pragma unroll
                for (int j = 0; j < 4; ++j) {
                    int gr = row0 + w * 32 + p * 16 + (l >> 4) * 4 + j;
                    if (gr < M) {
                        esrc[gr] = make_float2(pse[j], psg[j]);
                        edst[gr] = make_float2(pde[j], pdg[j]);
                    }
                }
            }
        }
#pragma unroll
        for (int n = 0; n < 8; n++)
#pragma unroll
            for (int j = 0; j < 4; j++)
                epi[(w * 16 + (l >> 4) * 4 + j) * 128 + n * 16 + (l & 15)] = f2bf(acc[p][n][j]);
        __syncthreads();
        int er = tid >> 2, sgm = tid & 3;
        int grow2 = row0 + 32 * (er >> 4) + 16 * p + (er & 15);
        if (grow2 < M) {
            const s16x8* src = (const s16x8*)(epi + er * 128 + sgm * 32);
            s16x8* dst = (s16x8*)(hh + (size_t)grow2 * 128 + sgm * 32);
#pragma unroll
            for (int q = 0; q < 4; q++) dst[q] = src[q];
        }
        __syncthreads();
    }
}

// ==================== bucket CSR finalize ====================
__global__ __launch_bounds__(256) void bucket_csr_k(const int* __restrict__ bcnt,
                                                    const int* __restrict__ bucket_base,
                                                    const int* __restrict__ csr_base,
                                                    const int* __restrict__ ebuf, int M,
                                                    int* __restrict__ row_start,
                                                    int* __restrict__ deg,
                                                    int* __restrict__ srcs) {
    int b = blockIdx.x, tid = threadIdx.x;
    int nE = bcnt[b];
    int ebase = bucket_base[b];
    int cbase = csr_base[b];
    int n0 = b << 9;
    int nloc = min(512, M - n0);
    __shared__ int cnt[512], sa[512], sb[512], cur[512];
#pragma unroll
    for (int k = 0; k < 2; ++k) {
        int i = tid + k * 256;
        cnt[i] = (i < nloc) ? 1 : 0;   // self loop
    }
    __syncthreads();
    for (int j = tid; j < nE; j += 256)
        atomicAdd(&cnt[ebuf[ebase + j] >> 17], 1);
    __syncthreads();
#pragma unroll
    for (int k = 0; k < 2; ++k) { int i = tid + k * 256; sa[i] = cnt[i]; }
    __syncthreads();
    int* a = sa; int* bb = sb;
    for (int off = 1; off < 512; off <<= 1) {
#pragma unroll
        for (int k = 0; k < 2; ++k) {
            int i = tid + k * 256;
            bb[i] = a[i] + (i >= off ? a[i - off] : 0);
        }
        __syncthreads();
        int* t = a; a = bb; bb = t;
    }
#pragma unroll
    for (int k = 0; k < 2; ++k) {
        int i = tid + k * 256;
        int excl = a[i] - cnt[i];
        cur[i] = excl;
        if (i < nloc) {
            row_start[n0 + i] = cbase + excl;
            deg[n0 + i] = cnt[i];
            srcs[cbase + excl] = n0 + i;   // self loop first
            cur[i] = excl + 1;
        }
    }
    __syncthreads();
    for (int j = tid; j < nE; j += 256) {
        int p = ebuf[ebase + j];
        int dl = p >> 17, src = p & 0x1FFFF;
        int pos = atomicAdd(&cur[dl], 1);
        srcs[cbase + pos] = src;
    }
}

// ==================== per-node: quarter-wave edges, 4 gathers in flight ====================
__global__ void node_acc_k(const int* __restrict__ srcs, const int* __restrict__ row_start,
                           const int* __restrict__ deg,
                           const float2* __restrict__ esrc, const float2* __restrict__ edst,
                           const unsigned short* __restrict__ hh,
                           const float* __restrict__ be, const float* __restrict__ ge,
                           const float* __restrict__ bte, const float* __restrict__ rme,
                           const float* __restrict__ rve,
                           const float* __restrict__ bg, const float* __restrict__ gg,
                           const float* __restrict__ btg, const float* __restrict__ rmg,
                           const float* __restrict__ rvg,
                           const float* __restrict__ clsW, const float* __restrict__ clsb,
                           float* __restrict__ y, float* __restrict__ s_out, int M) {
    int n = blockIdx.x * 4 + (threadIdx.x >> 6);
    int l = threadIdx.x & 63;
    if (n >= M) return;
    int beg = row_start[n];
    int cnt = deg[n];
    int qh = l >> 4;
    int li = l & 15;
    int layer = li >> 3;
    float2 ed = edst[n];
    float edv = layer ? ed.y : ed.x;
    const int* sp = srcs + beg;
    const char* hb = (const char*)hh + (unsigned)li * 16;
    float a0 = 0.f, a1 = 0.f, a2 = 0.f, a3 = 0.f;
    float a4 = 0.f, a5 = 0.f, a6 = 0.f, a7 = 0.f, zacc = 0.f;
    int j = 0;
    for (; j + 16 <= cnt; j += 16) {
        int s0 = sp[j + qh];
        int s1 = sp[j + 4 + qh];
        int s2 = sp[j + 8 + qh];
        int s3 = sp[j + 12 + qh];
        float2 e0 = esrc[s0], e1 = esrc[s1], e2 = esrc[s2], e3 = esrc[s3];
        uint4 h0 = *(const uint4*)(hb + ((size_t)(unsigned)s0 << 8));
        uint4 h1 = *(const uint4*)(hb + ((size_t)(unsigned)s1 << 8));
        uint4 h2 = *(const uint4*)(hb + ((size_t)(unsigned)s2 << 8));
        uint4 h3 = *(const uint4*)(hb + ((size_t)(unsigned)s3 << 8));
        float p0 = __expf(lrelu((layer ? e0.y : e0.x) + edv));
        float p1 = __expf(lrelu((layer ? e1.y : e1.x) + edv));
        float p2 = __expf(lrelu((layer ? e2.y : e2.x) + edv));
        float p3 = __expf(lrelu((layer ? e3.y : e3.x) + edv));
        zacc += (p0 + p1) + (p2 + p3);
        a0 += p0 * bf_lo(h0.x); a1 += p0 * bf_hi(h0.x);
        a2 += p0 * bf_lo(h0.y); a3 += p0 * bf_hi(h0.y);
        a4 += p0 * bf_lo(h0.z); a5 += p0 * bf_hi(h0.z);
        a6 += p0 * bf_lo(h0.w); a7 += p0 * bf_hi(h0.w);
        a0 += p1 * bf_lo(h1.x); a1 += p1 * bf_hi(h1.x);
        a2 += p1 * bf_lo(h1.y); a3 += p1 * bf_hi(h1.y);
        a4 += p1 * bf_lo(h1.z); a5 += p1 * bf_hi(h1.z);
        a6 += p1 * bf_lo(h1.w); a7 += p1 * bf_hi(h1.w);
        a0 += p2 * bf_lo(h2.x); a1 += p2 * bf_hi(h2.x);
        a2 += p2 * bf_lo(h2.y); a3 += p2 * bf_hi(h2.y);
        a4 += p2 * bf_lo(h2.z); a5 += p2 * bf_hi(h2.z);
        a6 += p2 * bf_lo(h2.w); a7 += p2 * bf_hi(h2.w);
        a0 += p3 * bf_lo(h3.x); a1 += p3 * bf_hi(h3.x);
        a2 += p3 * bf_lo(h3.y); a3 += p3 * bf_hi(h3.y);
        a4 += p3 * bf_lo(h3.z); a5 += p3 * bf_hi(h3.z);
        a6 += p3 * bf_lo(h3.w); a7 += p3 * bf_hi(h3.w);
    }
    for (; j + 8 <= cnt; j += 8) {
        int s0 = sp[j + qh];
        int s1 = sp[j + 4 + qh];
        float2 e0 = esrc[s0];
        float2 e1 = esrc[s1];
        uint4 h0 = *(const uint4*)(hb + ((size_t)(unsigned)s0 << 8));
        uint4 h1 = *(const uint4*)(hb + ((size_t)(unsigned)s1 << 8));
        float p0 = __expf(lrelu((layer ? e0.y : e0.x) + edv));
        float p1 = __expf(lrelu((layer ? e1.y : e1.x) + edv));
        zacc += p0 + p1;
        a0 += p0 * bf_lo(h0.x); a1 += p0 * bf_hi(h0.x);
        a2 += p0 * bf_lo(h0.y); a3 += p0 * bf_hi(h0.y);
        a4 += p0 * bf_lo(h0.z); a5 += p0 * bf_hi(h0.z);
        a6 += p0 * bf_lo(h0.w); a7 += p0 * bf_hi(h0.w);
        a0 += p1 * bf_lo(h1.x); a1 += p1 * bf_hi(h1.x);
        a2 += p1 * bf_lo(h1.y); a3 += p1 * bf_hi(h1.y);
        a4 += p1 * bf_lo(h1.z); a5 += p1 * bf_hi(h1.z);
        a6 += p1 * bf_lo(h1.w); a7 += p1 * bf_hi(h1.w);
    }
    for (; j < cnt; j += 4) {
        int idx = j + qh;
        if (idx < cnt) {
            int s = sp[idx];
            float2 e = esrc[s];
            uint4 h = *(const uint4*)(hb + ((size_t)(unsigned)s << 8));
            float p = __expf(lrelu((layer ? e.y : e.x) + edv));
            zacc += p;
            a0 += p * bf_lo(h.x); a1 += p * bf_hi(h.x);
            a2 += p * bf_lo(h.y); a3 += p * bf_hi(h.y);
            a4 += p * bf_lo(h.z); a5 += p * bf_hi(h.z);
            a6 += p * bf_lo(h.w); a7 += p * bf_hi(h.w);
        }
    }
    a0 += __shfl_xor(a0, 16, 64); a0 += __shfl_xor(a0, 32, 64);
    a1 += __shfl_xor(a1, 16, 64); a1 += __shfl_xor(a1, 32, 64);
    a2 += __shfl_xor(a2, 16, 64); a2 += __shfl_xor(a2, 32, 64);
    a3 += __shfl_xor(a3, 16, 64); a3 += __shfl_xor(a3, 32, 64);
    a4 += __shfl_xor(a4, 16, 64); a4 += __shfl_xor(a4, 32, 64);
    a5 += __shfl_xor(a5, 16, 64); a5 += __shfl_xor(a5, 32, 64);
    a6 += __shfl_xor(a6, 16, 64); a6 += __shfl_xor(a6, 32, 64);
    a7 += __shfl_xor(a7, 16, 64); a7 += __shfl_xor(a7, 32, 64);
    zacc += __shfl_xor(zacc, 16, 64); zacc += __shfl_xor(zacc, 32, 64);

    if (qh == 0) {
        float rz = 1.f / zacc;
        float o0 = a0 * rz, o1 = a1 * rz, o2 = a2 * rz, o3 = a3 * rz;
        float o4 = a4 * rz, o5 = a5 * rz, o6 = a6 * rz, o7 = a7 * rz;
        int cb = (li & 7) * 2;
        const float4* bp  = (const float4*)(layer ? bg  : be);
        const float4* rmp = (const float4*)(layer ? rmg : rme);
        const float4* rvp = (const float4*)(layer ? rvg : rve);
        const float4* gp4 = (const float4*)(layer ? gg  : ge);
        const float4* btp = (const float4*)(layer ? btg : bte);
        float4 bA = bp[cb],  bB = bp[cb + 1];
        float4 rmA = rmp[cb], rmB = rmp[cb + 1];
        float4 rvA = rvp[cb], rvB = rvp[cb + 1];
        float4 gA = gp4[cb],  gB = gp4[cb + 1];
        float4 btA = btp[cb], btB = btp[cb + 1];
        o0 = (fmaxf(o0 + bA.x, 0.f) - rmA.x) * rsqrtf(rvA.x + BN_EPS) * gA.x + btA.x;
        o1 = (fmaxf(o1 + bA.y, 0.f) - rmA.y) * rsqrtf(rvA.y + BN_EPS) * gA.y + btA.y;
        o2 = (fmaxf(o2 + bA.z, 0.f) - rmA.z) * rsqrtf(rvA.z + BN_EPS) * gA.z + btA.z;
        o3 = (fmaxf(o3 + bA.w, 0.f) - rmA.w) * rsqrtf(rvA.w + BN_EPS) * gA.w + btA.w;
        o4 = (fmaxf(o4 + bB.x, 0.f) - rmB.x) * rsqrtf(rvB.x + BN_EPS) * gB.x + btB.x;
        o5 = (fmaxf(o5 + bB.y, 0.f) - rmB.y) * rsqrtf(rvB.y + BN_EPS) * gB.y + btB.y;
        o6 = (fmaxf(o6 + bB.z, 0.f) - rmB.z) * rsqrtf(rvB.z + BN_EPS) * gB.z + btB.z;
        o7 = (fmaxf(o7 + bB.w, 0.f) - rmB.w) * rsqrtf(rvB.w + BN_EPS) * gB.w + btB.w;
        if (layer == 0) {
            float4* so = (float4*)(s_out + (size_t)n * 64 + (li & 7) * 8);
            so[0] = make_float4(o0, o1, o2, o3);
            so[1] = make_float4(o4, o5, o6, o7);
        } else {
            float4 wA = ((const float4*)clsW)[cb];
            float4 wB = ((const float4*)clsW)[cb + 1];
            float t = o0 * wA.x + o1 * wA.y + o2 * wA.z + o3 * wA.w
                    + o4 * wB.x + o5 * wB.y + o6 * wB.z + o7 * wB.w;
            t += __shfl_xor(t, 1, 64);
            t += __shfl_xor(t, 2, 64);
            t += __shfl_xor(t, 4, 64);
            if (li == 8) y[n] = t + clsb[0];
        }
    }
}

extern "C" void kernel_launch(void* const* d_in, const int* in_sizes, int n_in,
                              void* d_out, int out_size, void* d_ws, size_t ws_size,
                              hipStream_t stream) {
    const float* g        = (const float*)d_in[0];
    const int*   x        = (const int*)d_in[1];
    const float* est_W    = (const float*)d_in[2];
    const float* est_asrc = (const float*)d_in[3];
    const float* est_adst = (const float*)d_in[4];
    const float* est_bias = (const float*)d_in[5];
    const float* est_gamma= (const float*)d_in[6];
    const float* est_beta = (const float*)d_in[7];
    const float* est_rmean= (const float*)d_in[8];
    const float* est_rvar = (const float*)d_in[9];
    const float* gnn_W    = (const float*)d_in[10];
    const float* gnn_asrc = (const float*)d_in[11];
    const float* gnn_adst = (const float*)d_in[12];
    const float* gnn_bias = (const float*)d_in[13];
    const float* gnn_gamma= (const float*)d_in[14];
    const float* gnn_beta = (const float*)d_in[15];
    const float* gnn_rmean= (const float*)d_in[16];
    const float* gnn_rvar = (const float*)d_in[17];
    const float* cls_W    = (const float*)d_in[18];
    const float* cls_b    = (const float*)d_in[19];

    const int M  = in_sizes[0] / NFEAT;   // 100000
    const int E  = in_sizes[1] / 2;       // 1600000
    const int Et = E + M;
    const int NBKT = (M + 511) >> 9;      // 196
    const int NEB  = (E + 8191) / 8192;   // edge blocks (32 edges/thread) = 196
    const int GB   = (M + 127) / 128;     // gemm blocks = 782

    float* y_out = (float*)d_out;         // [M]
    float* s_out = y_out + M;             // [M*64]

    char* base = (char*)d_ws;
    unsigned short* hh = (unsigned short*)base;                 // M*128 bf16
    size_t off = (size_t)M * 128 * 2;
    char* Wt = base + off;                  off += 81920;
    float2* esrc = (float2*)(base + off);   off += (size_t)M * 8;
    float2* edst = (float2*)(base + off);   off += (size_t)M * 8;
    int* deg       = (int*)(base + off);    off += (size_t)M * 4;
    int* row_start = (int*)(base + off);    off += (size_t)M * 4;
    int* srcs      = (int*)(base + off);    off += (size_t)Et * 4;
    int* ebuf      = (int*)(base + off);    off += (size_t)E * 4;
    int* bcnt        = (int*)(base + off);  off += 256 * 4;
    int* bucket_base = (int*)(base + off);  off += 256 * 4;
    int* bcursor     = (int*)(base + off);  off += 256 * 4;
    int* csr_base    = (int*)(base + off);  off += 256 * 4;

    prep_w_k<<<128, 256, 0, stream>>>(est_W, gnn_W, (unsigned short*)Wt, bcnt);
    bucket_hist_k<<<NEB, 256, 0, stream>>>(x, E, bcnt);
    bucket_scan_k<<<1, 256, 0, stream>>>(bcnt, M, NBKT, bucket_base, bcursor, csr_base);
    stage3_k<<<GB + NEB, 256, 0, stream>>>(g, Wt, hh,
                                           est_asrc, est_adst, gnn_asrc, gnn_adst,
                                           esrc, edst, M, GB, x, E, bcursor, ebuf);
    bucket_csr_k<<<NBKT, 256, 0, stream>>>(bcnt, bucket_base, csr_base, ebuf, M,
                                           row_start, deg, srcs);
    node_acc_k<<<(M + 3) / 4, 256, 0, stream>>>(srcs, row_start, deg, esrc, edst, hh,
                                                est_bias, est_gamma, est_beta, est_rmean, est_rvar,
                                                gnn_bias, gnn_gamma, gnn_beta, gnn_rmean, gnn_rvar,
                                                cls_W, cls_b, y_out, s_out, M);
}